// Round 11
// baseline (30.886 us; speedup 1.0000x reference)
//
#include <hip/hip_runtime.h>

// 3D median filter 3x3x3, stride 1, reflect padding.
// x: (2, 1, 160, 160, 160) fp32 -> same shape. Median = rank 13 (0-based) of 27.
// Round 10: R9 (full-width LDS plane ring, global_load_lds fills, counted
// vmcnt + raw s_barrier) with the vmcnt off-by-one FIXED: steady-state wait is
// vmcnt(4) (queue @iter j = [FF(pair j+2), SS(j-1)] = 4 newest; anything older
// -- incl. the pair j+1 we consume -- is complete), restoring the 2-iteration
// prefetch slack the 6-slot ring was built for. R9's vmcnt(2) waited on fills
// issued only 1 iter ago => per-iteration HBM stall, block-wide (barrier).
// Plus: tree-ified sel13 (dep depth 9->5) and sortp(sD) moved under the math.

typedef __fp16 hf2 __attribute__((ext_vector_type(2)));
typedef __fp16 hf4 __attribute__((ext_vector_type(4)));

#define DEV __device__ __forceinline__

DEV hf4 hmin4(hf4 a, hf4 b) { return __builtin_elementwise_min(a, b); }
DEV hf4 hmax4(hf4 a, hf4 b) { return __builtin_elementwise_max(a, b); }
DEV void ce(hf4& a, hf4& b) { hf4 lo = hmin4(a, b); hf4 hi = hmax4(a, b); a = lo; b = hi; }
DEV hf2 pk2(float a, float b) { return __builtin_amdgcn_cvt_pkrtz(a, b); }
DEV hf4 cat(hf2 a, hf2 b) { return __builtin_shufflevector(a, b, 0, 1, 2, 3); }

DEV void sort3(hf4& a, hf4& b, hf4& c) { ce(a, b); ce(a, c); ce(b, c); }

// Batcher odd-even merges of small sorted sequences (verified exact, rounds 1-9).
DEV void merge21(hf4 a0, hf4 a1, hf4 b0, hf4 z[3]) {
    hf4 e0 = a0, e1 = b0; ce(e0, e1);
    z[0] = e0; z[1] = a1; z[2] = e1; ce(z[1], z[2]);
}
DEV void merge22(hf4 a0, hf4 a1, hf4 b0, hf4 b1, hf4 z[4]) {
    hf4 p0 = a0, p1 = b0; ce(p0, p1);
    hf4 q0 = a1, q1 = b1; ce(q0, q1);
    z[0] = p0; z[1] = q0; z[2] = p1; ce(z[1], z[2]); z[3] = q1;
}
DEV void merge31(hf4 a0, hf4 a1, hf4 a2, hf4 b0, hf4 z[4]) {
    hf4 e[3]; merge21(a0, a2, b0, e);
    z[0] = e[0]; z[1] = a1; z[2] = e[1]; ce(z[1], z[2]); z[3] = e[2];
}
DEV void merge32(hf4 a0, hf4 a1, hf4 a2, hf4 b0, hf4 b1, hf4 z[5]) {
    hf4 e[3]; merge21(a0, a2, b0, e);
    hf4 o0 = a1, o1 = b1; ce(o0, o1);
    z[0] = e[0];
    z[1] = o0; z[2] = e[1]; ce(z[1], z[2]);
    z[3] = o1; z[4] = e[2]; ce(z[3], z[4]);
}
DEV void merge33(const hf4 a[3], const hf4 b[3], hf4 z[6]) {
    hf4 e[4]; merge22(a[0], a[2], b[0], b[2], e);
    hf4 o0 = a[1], o1 = b[1]; ce(o0, o1);
    z[0] = e[0];
    z[1] = o0; z[2] = e[1]; ce(z[1], z[2]);
    z[3] = o1; z[4] = e[2]; ce(z[3], z[4]);
    z[5] = e[3];
}
DEV void merge63(const hf4 a[6], const hf4 b[3], hf4 z[9]) {
    hf4 e[5]; merge32(a[0], a[2], a[4], b[0], b[2], e);
    hf4 o[4]; merge31(a[1], a[3], a[5], b[1], o);
    z[0] = e[0];
    z[1] = o[0]; z[2] = e[1]; ce(z[1], z[2]);
    z[3] = o[1]; z[4] = e[2]; ce(z[3], z[4]);
    z[5] = o[2]; z[6] = e[3]; ce(z[5], z[6]);
    z[7] = o[3]; z[8] = e[4]; ce(z[7], z[8]);
}
DEV void merge44(const hf4 a[4], const hf4 b[4], hf4 z[8]) {
    hf4 e[4]; merge22(a[0], a[2], b[0], b[2], e);
    hf4 o[4]; merge22(a[1], a[3], b[1], b[3], o);
    z[0] = e[0];
    z[1] = o[0]; z[2] = e[1]; ce(z[1], z[2]);
    z[3] = o[1]; z[4] = e[2]; ce(z[3], z[4]);
    z[5] = o[2]; z[6] = e[3]; ce(z[5], z[6]);
    z[7] = o[3];
}
DEV void merge55(const hf4 a[5], const hf4 b[5], hf4 z[10]) {
    hf4 ae[3] = {a[0], a[2], a[4]}, be[3] = {b[0], b[2], b[4]};
    hf4 e[6]; merge33(ae, be, e);
    hf4 o[4]; merge22(a[1], a[3], b[1], b[3], o);
    z[0] = e[0];
    z[1] = o[0]; z[2] = e[1]; ce(z[1], z[2]);
    z[3] = o[1]; z[4] = e[2]; ce(z[3], z[4]);
    z[5] = o[2]; z[6] = e[3]; ce(z[5], z[6]);
    z[7] = o[3]; z[8] = e[4]; ce(z[7], z[8]);
    z[9] = e[5];
}
DEV void merge99(const hf4 a[9], const hf4 b[9], hf4 z[18]) {
    hf4 ae[5] = {a[0], a[2], a[4], a[6], a[8]};
    hf4 be[5] = {b[0], b[2], b[4], b[6], b[8]};
    hf4 e[10]; merge55(ae, be, e);
    hf4 ao[4] = {a[1], a[3], a[5], a[7]};
    hf4 bo[4] = {b[1], b[3], b[5], b[7]};
    hf4 o[8]; merge44(ao, bo, o);
    z[0] = e[0];
#pragma unroll
    for (int i = 0; i < 8; i++) {
        z[2 * i + 1] = o[i];
        z[2 * i + 2] = e[i + 1];
        ce(z[2 * i + 1], z[2 * i + 2]);
    }
    z[17] = e[9];
}

// rank-13-of-27, tree form: med = min(E[13], min_i max(R[i], E[12-i])).
// (identity verified exact in round 1; tree shortens the dep chain 9 -> 5)
DEV hf4 sel13(const hf4 E[18], const hf4 R[9]) {
    hf4 t0 = hmax4(R[0], E[12]), t1 = hmax4(R[1], E[11]);
    hf4 t2 = hmax4(R[2], E[10]), t3 = hmax4(R[3], E[9]);
    hf4 t4 = hmax4(R[4], E[8]),  t5 = hmax4(R[5], E[7]);
    hf4 t6 = hmax4(R[6], E[6]),  t7 = hmax4(R[7], E[5]);
    hf4 t8 = hmax4(R[8], E[4]);
    hf4 a = hmin4(t0, t1), b = hmin4(t2, t3);
    hf4 c = hmin4(t4, t5), d = hmin4(t6, t7);
    hf4 e = hmin4(hmin4(a, b), hmin4(c, d));
    return hmin4(hmin4(e, t8), E[13]);
}

constexpr int Bb = 2, Dd = 160, Hh = 160, Ww = 160;
constexpr int HW = Hh * Ww;          // 25600
constexpr int STRIP = 5;             // output rows per block
constexpr int NSTRIP = Hh / STRIP;   // 32
constexpr int CH = 10;               // z-chunk per block
constexpr int NCH = Dd / CH;         // 16
constexpr int TROWS = STRIP + 2;     // 7 (y-halo)
constexpr int PLANEF = TROWS * Ww;   // 1120 floats per plane tile
constexpr int NRING = 6;             // LDS plane ring slots
constexpr int NBLK = Bb * NCH * NSTRIP;  // 1024 blocks

typedef __attribute__((address_space(1))) const unsigned int gas_u32;
typedef __attribute__((address_space(3))) unsigned int las_u32;

// Counted wait + raw barrier (T3/T4). N chosen per wait site from the exact
// in-order vmem queue contents (fills first, stores newest): with <= N
// outstanding, every older fill -- i.e. the pair being consumed -- is done.
#define WAIT_BARRIER(N)                                                 \
    do {                                                                \
        asm volatile("s_waitcnt vmcnt(" #N ") lgkmcnt(0)" ::: "memory"); \
        __builtin_amdgcn_sched_barrier(0);                              \
        __builtin_amdgcn_s_barrier();                                   \
        __builtin_amdgcn_sched_barrier(0);                              \
    } while (0)

__global__ __launch_bounds__(256, 4) void MedianPool3d_68994354642979_kernel(
    const float* __restrict__ in, float* __restrict__ out) {
    __shared__ float lds[NRING * PLANEF];  // 26,880 B

    const int tid = threadIdx.x;
    int bid = blockIdx.x;
    const int ty = bid % NSTRIP; bid /= NSTRIP;
    const int zc = bid % NCH;
    const int b  = bid / NCH;
    const int z0 = zc * CH;
    const int y0 = ty * STRIP;

    const float* base = in + (size_t)b * Dd * HW;
    float* ob = out + (size_t)b * Dd * HW;

    // Fill plane m (global plane z0-1+m, z-reflected) into ring slot m%NRING.
    // 280 16B-chunks: every thread 1, threads 0..23 a 2nd (wave0 only).
    auto fill = [&](int m) {
        int p = z0 - 1 + m;
        p = (p < 0) ? 1 : ((p > Dd - 1) ? Dd - 2 : p);  // z reflect (±1 max)
        const float* pp = base + (size_t)p * HW;
        float* ldsb = &lds[(m % NRING) * PLANEF];
        {
            int row = tid / 40, c4 = tid % 40;
            int gy = y0 - 1 + row;
            gy = (gy < 0) ? 1 : ((gy > Hh - 1) ? Hh - 2 : gy);  // y reflect
            const float* src = pp + gy * Ww + c4 * 4;
            float* dst = ldsb + (size_t)(tid & ~63) * 4;  // wave-uniform base
            __builtin_amdgcn_global_load_lds((gas_u32*)src, (las_u32*)dst, 16, 0, 0);
        }
        if (tid < 24) {  // chunks 256..279 (row 6, cols 64..159)
            int c = 256 + tid;
            int c4 = c % 40;
            int gy = y0 + 5;
            gy = (gy > Hh - 1) ? Hh - 2 : gy;
            const float* src = pp + gy * Ww + c4 * 4;
            float* dst = ldsb + 256 * 4;
            __builtin_amdgcn_global_load_lds((gas_u32*)src, (las_u32*)dst, 16, 0, 0);
        }
    };

    // Compute site: 200 active threads -> (q, ly), 4 x-outputs each.
    const int q = tid % 40;
    const int ly = tid / 40;      // 0..4 active
    const int x0 = q * 4;
    const int cLi = (q == 0) ? 1 : (x0 - 1);          // x reflect via LDS col
    const int cRi = (q == 39) ? (Ww - 2) : (x0 + 4);

    auto sortp = [&](int m, hf4(&M)[9]) {
        const float* tb = &lds[(m % NRING) * PLANEF];
        hf4 r[3][3];
#pragma unroll
        for (int i = 0; i < 3; i++) {
            const float* rp = tb + (ly + i) * Ww;
            float4 v = *reinterpret_cast<const float4*>(rp + x0);  // ds_read_b128
            float a = rp[cLi], d = rp[cRi];
            hf2 pAL = pk2(a, v.x);
            hf2 pAC = pk2(v.x, v.y);
            hf2 pSH = pk2(v.y, v.z);
            hf2 pBC = pk2(v.z, v.w);
            hf2 pBR = pk2(v.w, d);
            r[i][0] = cat(pAL, pSH);
            r[i][1] = cat(pAC, pBC);
            r[i][2] = cat(pSH, pBR);
            sort3(r[i][0], r[i][1], r[i][2]);
        }
        hf4 s6[6]; merge33(r[0], r[1], s6);
        merge63(s6, r[2], M);
    };

    // Prologue: issue all 6 ring fills; wait for planes 0,1 (vmcnt(4): with
    // <=4 outstanding of 6, the oldest 2 -- planes 0,1 -- are complete; for
    // tid<24 (12 instrs) it covers planes 0..3 both-chunk. Sort planes 0,1.
    fill(0); fill(1);
    fill(2); fill(3);
    fill(4); fill(5);
    WAIT_BARRIER(4);

    hf4 SS[4][9];
    if (tid < 200) { sortp(0, SS[0]); sortp(1, SS[1]); }

#pragma unroll
    for (int j = 0; j < CH / 2; j++) {
        // Wait: pair j+1 (planes 2j+2, 2j+3) resident. Iter 0: queue still
        // holds up to 6 prologue fills -> vmcnt(2) (oldest 4 = planes 0..3).
        // Iters >=1: queue = [FF(pair j+2)@j-1, SS@j-1] = 4 -> vmcnt(4) means
        // everything older (pair j+1, filled @j-2) is complete. Stores sit
        // newest and never gate.
        if (j == 0) WAIT_BARRIER(2); else WAIT_BARRIER(4);

        if (2 * j + 7 <= CH + 1) { fill(2 * j + 6); fill(2 * j + 7); }  // pair j+3

        if (tid < 200) {
            const int sA = (2 * j) & 3;      // S[z-1]
            const int sB = (2 * j + 1) & 3;  // S[z]
            const int sC = (2 * j + 2) & 3;  // S[z+1]
            const int sD = (2 * j + 3) & 3;  // S[z+2]
            const int z = z0 + 2 * j;
            float* o0 = ob + (size_t)z * HW + (y0 + ly) * Ww + x0;  // 16B-aligned
            float* o1 = o0 + HW;

            sortp(2 * j + 2, SS[sC]);

            hf4 E[18];
            merge99(SS[sB], SS[sC], E);   // shared pair (z, z+1) -> used twice
            hf4 m0 = sel13(E, SS[sA]);    // output z : third plane z-1
            *reinterpret_cast<float4*>(o0) =
                make_float4((float)m0.x, (float)m0.y, (float)m0.z, (float)m0.w);

            sortp(2 * j + 3, SS[sD]);     // ds_reads hide under merge/sel math
            hf4 m1 = sel13(E, SS[sD]);    // output z+1 : third plane z+2
            *reinterpret_cast<float4*>(o1) =
                make_float4((float)m1.x, (float)m1.y, (float)m1.z, (float)m1.w);
        }
    }
}

extern "C" void kernel_launch(void* const* d_in, const int* in_sizes, int n_in,
                              void* d_out, int out_size, void* d_ws, size_t ws_size,
                              hipStream_t stream) {
    const float* x = (const float*)d_in[0];
    float* out = (float*)d_out;
    MedianPool3d_68994354642979_kernel<<<NBLK, 256, 0, stream>>>(x, out);
}

// Round 12
// 28.547 us; speedup vs baseline: 1.0820x; 1.0820x over previous
//
#include <hip/hip_runtime.h>

// 3D median filter 3x3x3, stride 1, reflect padding.
// x: (2, 1, 160, 160, 160) fp32 -> same shape. Median = rank 13 (0-based) of 27.
// Round 11: R7 pipeline + EDGE TAPS VIA __shfl. Old: 9 vmem/plane/lane
// (dword+dwordx4+dword x3 rows) = ~144 L1 line-requests per wave-plane.
// New: 3 dwordx4 + 6 shfl (LDS pipe) + 2 rare 1-lane seam loads = ~50
// line-requests. Attacks the saturated vector-memory front-end that pinned
// VALUBusy at ~30% across R3-R10 regardless of occupancy/scheduling.

typedef __fp16 hf2 __attribute__((ext_vector_type(2)));
typedef __fp16 hf4 __attribute__((ext_vector_type(4)));

#define DEV __device__ __forceinline__
#define SCHED_FENCE() __builtin_amdgcn_sched_barrier(0)

DEV hf4 hmin4(hf4 a, hf4 b) { return __builtin_elementwise_min(a, b); }
DEV hf4 hmax4(hf4 a, hf4 b) { return __builtin_elementwise_max(a, b); }
DEV void ce(hf4& a, hf4& b) { hf4 lo = hmin4(a, b); hf4 hi = hmax4(a, b); a = lo; b = hi; }
DEV hf2 pk2(float a, float b) { return __builtin_amdgcn_cvt_pkrtz(a, b); }
DEV hf4 cat(hf2 a, hf2 b) { return __builtin_shufflevector(a, b, 0, 1, 2, 3); }

DEV void sort3(hf4& a, hf4& b, hf4& c) { ce(a, b); ce(a, c); ce(b, c); }

// Batcher odd-even merges of small sorted sequences (verified exact, rounds 1-10).
DEV void merge21(hf4 a0, hf4 a1, hf4 b0, hf4 z[3]) {
    hf4 e0 = a0, e1 = b0; ce(e0, e1);
    z[0] = e0; z[1] = a1; z[2] = e1; ce(z[1], z[2]);
}
DEV void merge22(hf4 a0, hf4 a1, hf4 b0, hf4 b1, hf4 z[4]) {
    hf4 p0 = a0, p1 = b0; ce(p0, p1);
    hf4 q0 = a1, q1 = b1; ce(q0, q1);
    z[0] = p0; z[1] = q0; z[2] = p1; ce(z[1], z[2]); z[3] = q1;
}
DEV void merge31(hf4 a0, hf4 a1, hf4 a2, hf4 b0, hf4 z[4]) {
    hf4 e[3]; merge21(a0, a2, b0, e);
    z[0] = e[0]; z[1] = a1; z[2] = e[1]; ce(z[1], z[2]); z[3] = e[2];
}
DEV void merge32(hf4 a0, hf4 a1, hf4 a2, hf4 b0, hf4 b1, hf4 z[5]) {
    hf4 e[3]; merge21(a0, a2, b0, e);
    hf4 o0 = a1, o1 = b1; ce(o0, o1);
    z[0] = e[0];
    z[1] = o0; z[2] = e[1]; ce(z[1], z[2]);
    z[3] = o1; z[4] = e[2]; ce(z[3], z[4]);
}
DEV void merge33(const hf4 a[3], const hf4 b[3], hf4 z[6]) {
    hf4 e[4]; merge22(a[0], a[2], b[0], b[2], e);
    hf4 o0 = a[1], o1 = b[1]; ce(o0, o1);
    z[0] = e[0];
    z[1] = o0; z[2] = e[1]; ce(z[1], z[2]);
    z[3] = o1; z[4] = e[2]; ce(z[3], z[4]);
    z[5] = e[3];
}
DEV void merge63(const hf4 a[6], const hf4 b[3], hf4 z[9]) {
    hf4 e[5]; merge32(a[0], a[2], a[4], b[0], b[2], e);
    hf4 o[4]; merge31(a[1], a[3], a[5], b[1], o);
    z[0] = e[0];
    z[1] = o[0]; z[2] = e[1]; ce(z[1], z[2]);
    z[3] = o[1]; z[4] = e[2]; ce(z[3], z[4]);
    z[5] = o[2]; z[6] = e[3]; ce(z[5], z[6]);
    z[7] = o[3]; z[8] = e[4]; ce(z[7], z[8]);
}
DEV void merge44(const hf4 a[4], const hf4 b[4], hf4 z[8]) {
    hf4 e[4]; merge22(a[0], a[2], b[0], b[2], e);
    hf4 o[4]; merge22(a[1], a[3], b[1], b[3], o);
    z[0] = e[0];
    z[1] = o[0]; z[2] = e[1]; ce(z[1], z[2]);
    z[3] = o[1]; z[4] = e[2]; ce(z[3], z[4]);
    z[5] = o[2]; z[6] = e[3]; ce(z[5], z[6]);
    z[7] = o[3];
}
DEV void merge55(const hf4 a[5], const hf4 b[5], hf4 z[10]) {
    hf4 ae[3] = {a[0], a[2], a[4]}, be[3] = {b[0], b[2], b[4]};
    hf4 e[6]; merge33(ae, be, e);
    hf4 o[4]; merge22(a[1], a[3], b[1], b[3], o);
    z[0] = e[0];
    z[1] = o[0]; z[2] = e[1]; ce(z[1], z[2]);
    z[3] = o[1]; z[4] = e[2]; ce(z[3], z[4]);
    z[5] = o[2]; z[6] = e[3]; ce(z[5], z[6]);
    z[7] = o[3]; z[8] = e[4]; ce(z[7], z[8]);
    z[9] = e[5];
}
DEV void merge99(const hf4 a[9], const hf4 b[9], hf4 z[18]) {
    hf4 ae[5] = {a[0], a[2], a[4], a[6], a[8]};
    hf4 be[5] = {b[0], b[2], b[4], b[6], b[8]};
    hf4 e[10]; merge55(ae, be, e);
    hf4 ao[4] = {a[1], a[3], a[5], a[7]};
    hf4 bo[4] = {b[1], b[3], b[5], b[7]};
    hf4 o[8]; merge44(ao, bo, o);
    z[0] = e[0];
#pragma unroll
    for (int i = 0; i < 8; i++) {
        z[2 * i + 1] = o[i];
        z[2 * i + 2] = e[i + 1];
        ce(z[2 * i + 1], z[2 * i + 2]);
    }
    z[17] = e[9];
}

// rank-13-of-27, tree form: med = min(E[13], min_i max(R[i], E[12-i])).
// (identity verified exact in round 1; tree shortens the dep chain 9 -> 5)
DEV hf4 sel13(const hf4 E[18], const hf4 R[9]) {
    hf4 t0 = hmax4(R[0], E[12]), t1 = hmax4(R[1], E[11]);
    hf4 t2 = hmax4(R[2], E[10]), t3 = hmax4(R[3], E[9]);
    hf4 t4 = hmax4(R[4], E[8]),  t5 = hmax4(R[5], E[7]);
    hf4 t6 = hmax4(R[6], E[6]),  t7 = hmax4(R[7], E[5]);
    hf4 t8 = hmax4(R[8], E[4]);
    hf4 a = hmin4(t0, t1), b = hmin4(t2, t3);
    hf4 c = hmin4(t4, t5), d = hmin4(t6, t7);
    hf4 e = hmin4(hmin4(a, b), hmin4(c, d));
    return hmin4(hmin4(e, t8), E[13]);
}

// Raw prefetched plane: 3 row-vectors + seam taps (valid on lanes 0/63 only).
struct RawPlane {
    float4 P[3];
    float aL[3];   // lane 0 & q>0 : col x0-1 of each row
    float dR[3];   // lane 63 & q<39: col x0+4 of each row
};

// Prefetch: 3 dwordx4 + (2 one-lane-masked dword batches for the wave seams).
DEV void load_plane(const float* __restrict__ pb, const int ro[3], int x0,
                    bool needL, bool needR, RawPlane& R) {
#pragma unroll
    for (int i = 0; i < 3; i++)
        R.P[i] = *reinterpret_cast<const float4*>(pb + ro[i] + x0);  // 16B-aligned
    if (needL) {  // lane 0, q>0: left taps from previous wave's quad
#pragma unroll
        for (int i = 0; i < 3; i++) R.aL[i] = pb[ro[i] + x0 - 1];
    }
    if (needR) {  // lane 63, q<39: right taps from next wave's quad
#pragma unroll
        for (int i = 0; i < 3; i++) R.dR[i] = pb[ro[i] + x0 + 4];
    }
}

// Consume: edge taps via cross-lane shuffle (lane l-1's v.w / lane l+1's v.x),
// reflect at row edges from own register, seam lanes from prefetched taps.
DEV void sortp(const RawPlane& R, int q, int l, hf4 M[9]) {
    hf4 r[3][3];
#pragma unroll
    for (int i = 0; i < 3; i++) {
        float4 v = R.P[i];
        float wL = __shfl_up(v.w, 1);
        float xR = __shfl_down(v.x, 1);
        float a = (l == 0) ? R.aL[i] : wL;
        float d = (l == 63) ? R.dR[i] : xR;
        a = (q == 0) ? v.y : a;        // x-reflect: col -1 -> col 1
        d = (q == 39) ? v.z : d;       // x-reflect: col 160 -> col 158
        hf2 pAL = pk2(a, v.x);
        hf2 pAC = pk2(v.x, v.y);
        hf2 pSH = pk2(v.y, v.z);   // right-taps of pair A == left-taps of pair B
        hf2 pBC = pk2(v.z, v.w);
        hf2 pBR = pk2(v.w, d);
        r[i][0] = cat(pAL, pSH);
        r[i][1] = cat(pAC, pBC);
        r[i][2] = cat(pSH, pBR);
        sort3(r[i][0], r[i][1], r[i][2]);
    }
    hf4 s6[6]; merge33(r[0], r[1], s6);
    merge63(s6, r[2], M);
}

constexpr int Bb = 2, Dd = 160, Hh = 160, Ww = 160;
constexpr int HW = Hh * Ww;            // 25600
constexpr int WQ = Ww / 4;             // 40 x-quads per row
constexpr int CH = 8;                  // z-chunk per thread (even)
constexpr int NCH = Dd / CH;           // 20
constexpr int TOTAL = Bb * NCH * Hh * WQ;  // 256,000 threads = 4000 waves

__global__ __launch_bounds__(256, 2) void MedianPool3d_68994354642979_kernel(
    const float* __restrict__ in, float* __restrict__ out) {
    int tid = blockIdx.x * 256 + threadIdx.x;
    const int l = threadIdx.x & 63;   // lane id (grid offsets are x256)
    int q = tid % WQ;
    int rest = tid / WQ;
    int y = rest % Hh;
    rest /= Hh;
    int chunk = rest % NCH;
    int b = rest / NCH;
    int x0 = q * 4;

    const bool needL = (l == 0) && (q != 0);
    const bool needR = (l == 63) && (q != WQ - 1);

    // reflect padding (jnp.pad mode="reflect", pad=1)
    int ym = (y == 0) ? 1 : y - 1;
    int yp = (y == Hh - 1) ? Hh - 2 : y + 1;
    int ro[3] = {ym * Ww, y * Ww, yp * Ww};

    const float* base = in + (size_t)b * Dd * HW;
    float* ob = out + (size_t)b * Dd * HW;
    int z0 = chunk * CH;

    auto planeptr = [&](int p) {
        if (p < 0) p = -p;                 // reflect(-1) = 1
        if (p >= Dd) p = 2 * Dd - 2 - p;   // reflect(160) = 158
        return base + (size_t)p * HW;
    };

    // 4-slot ring of sorted planes: plane (z0-1)+m -> slot m&3.
    hf4 SS[4][9];
    // Raw prefetch buffers: RT0 even-rel planes, RT1 odd-rel planes.
    RawPlane RT0 = {}, RT1 = {};

    {   // prologue: issue rel -1,0,1,2 together; sort -1,0,1; issue rel 3.
        RawPlane P0 = {}, P1 = {};
        load_plane(planeptr(z0 - 1), ro, x0, needL, needR, P0);
        load_plane(planeptr(z0),     ro, x0, needL, needR, P1);
        load_plane(planeptr(z0 + 1), ro, x0, needL, needR, RT1);
        load_plane(planeptr(z0 + 2), ro, x0, needL, needR, RT0);
        SCHED_FENCE();
        sortp(P0, q, l, SS[0]);   // S[z0-1]
        sortp(P1, q, l, SS[1]);   // S[z0]
        sortp(RT1, q, l, SS[2]);  // S[z0+1]
        load_plane(planeptr(z0 + 3), ro, x0, needL, needR, RT1);
        SCHED_FENCE();
    }

#pragma unroll
    for (int j = 0; j < CH / 2; j++) {
        const int z = z0 + 2 * j;
        const int sA = (2 * j) & 3;      // S[z-1]
        const int sB = (2 * j + 1) & 3;  // S[z]
        const int sC = (2 * j + 2) & 3;  // S[z+1]
        const int sD = (2 * j + 3) & 3;  // S[z+2]

        // consume RT0 (plane z+2, loaded a full iteration ago)
        sortp(RT0, q, l, SS[sD]);
        if (j < CH / 2 - 1)  // prefetch plane z+4 into RT0; pinned by the fence
            load_plane(planeptr(z + 4), ro, x0, needL, needR, RT0);
        SCHED_FENCE();

        hf4 E[18];
        merge99(SS[sB], SS[sC], E);      // shared pair (z, z+1) -> used twice
        hf4 m0 = sel13(E, SS[sA]);       // output z   : third plane z-1
        hf4 m1 = sel13(E, SS[sD]);       // output z+1 : third plane z+2

        float* o0 = ob + (size_t)z * HW + ro[1] + x0;   // 16B-aligned
        float* o1 = o0 + HW;
        *reinterpret_cast<float4*>(o0) =
            make_float4((float)m0.x, (float)m0.y, (float)m0.z, (float)m0.w);
        *reinterpret_cast<float4*>(o1) =
            make_float4((float)m1.x, (float)m1.y, (float)m1.z, (float)m1.w);

        if (j < CH / 2 - 1) {  // consume RT1 (plane z+3) into the retired slot
            sortp(RT1, q, l, SS[sA]);
            if (j < CH / 2 - 2)  // prefetch plane z+5 into RT1
                load_plane(planeptr(z + 5), ro, x0, needL, needR, RT1);
        }
        SCHED_FENCE();
    }
}

extern "C" void kernel_launch(void* const* d_in, const int* in_sizes, int n_in,
                              void* d_out, int out_size, void* d_ws, size_t ws_size,
                              hipStream_t stream) {
    const float* x = (const float*)d_in[0];
    float* out = (float*)d_out;
    constexpr int threads = 256;
    constexpr int blocks = TOTAL / threads;  // 1000 exactly
    MedianPool3d_68994354642979_kernel<<<blocks, threads, 0, stream>>>(x, out);
}

// Round 14
// 27.919 us; speedup vs baseline: 1.1063x; 1.0225x over previous
//
#include <hip/hip_runtime.h>

// 3D median filter 3x3x3, stride 1, reflect padding.
// x: (2, 1, 160, 160, 160) fp32 -> same shape. Median = rank 13 (0-based) of 27.
// Round 13 (= R12 with asm operand fix): ALL global loads are asm volatile
// global_load_* (flat 64-bit vaddr + off form), prefetch depth 2 (4-plane
// ring), hand-counted s_waitcnt vmcnt(N) + sched_barrier(0). The compiler
// cannot sink/collapse volatile asm, so the pipeline provably stays live
// (expect VGPR ~200). Compute: hf4 packed-f16 median network (rounds 5-11).

typedef __fp16 hf2 __attribute__((ext_vector_type(2)));
typedef __fp16 hf4 __attribute__((ext_vector_type(4)));
typedef float f4 __attribute__((ext_vector_type(4)));

#define DEV __device__ __forceinline__

// counted wait: allow N outstanding vmem ops; fence scheduler both ways
// (rule #18: VALU hoists past inline-asm waitcnt without sched_barrier).
#define VMWAIT(N)                                                      \
    do {                                                               \
        asm volatile("s_waitcnt vmcnt(" #N ")" ::: "memory");          \
        __builtin_amdgcn_sched_barrier(0);                             \
    } while (0)

DEV hf4 hmin4(hf4 a, hf4 b) { return __builtin_elementwise_min(a, b); }
DEV hf4 hmax4(hf4 a, hf4 b) { return __builtin_elementwise_max(a, b); }
DEV void ce(hf4& a, hf4& b) { hf4 lo = hmin4(a, b); hf4 hi = hmax4(a, b); a = lo; b = hi; }
DEV hf2 pk2(float a, float b) { return __builtin_amdgcn_cvt_pkrtz(a, b); }
DEV hf4 cat(hf2 a, hf2 b) { return __builtin_shufflevector(a, b, 0, 1, 2, 3); }

DEV void sort3(hf4& a, hf4& b, hf4& c) { ce(a, b); ce(a, c); ce(b, c); }

// Batcher odd-even merges (verified exact, rounds 1-11).
DEV void merge21(hf4 a0, hf4 a1, hf4 b0, hf4 z[3]) {
    hf4 e0 = a0, e1 = b0; ce(e0, e1);
    z[0] = e0; z[1] = a1; z[2] = e1; ce(z[1], z[2]);
}
DEV void merge22(hf4 a0, hf4 a1, hf4 b0, hf4 b1, hf4 z[4]) {
    hf4 p0 = a0, p1 = b0; ce(p0, p1);
    hf4 q0 = a1, q1 = b1; ce(q0, q1);
    z[0] = p0; z[1] = q0; z[2] = p1; ce(z[1], z[2]); z[3] = q1;
}
DEV void merge31(hf4 a0, hf4 a1, hf4 a2, hf4 b0, hf4 z[4]) {
    hf4 e[3]; merge21(a0, a2, b0, e);
    z[0] = e[0]; z[1] = a1; z[2] = e[1]; ce(z[1], z[2]); z[3] = e[2];
}
DEV void merge32(hf4 a0, hf4 a1, hf4 a2, hf4 b0, hf4 b1, hf4 z[5]) {
    hf4 e[3]; merge21(a0, a2, b0, e);
    hf4 o0 = a1, o1 = b1; ce(o0, o1);
    z[0] = e[0];
    z[1] = o0; z[2] = e[1]; ce(z[1], z[2]);
    z[3] = o1; z[4] = e[2]; ce(z[3], z[4]);
}
DEV void merge33(const hf4 a[3], const hf4 b[3], hf4 z[6]) {
    hf4 e[4]; merge22(a[0], a[2], b[0], b[2], e);
    hf4 o0 = a[1], o1 = b[1]; ce(o0, o1);
    z[0] = e[0];
    z[1] = o0; z[2] = e[1]; ce(z[1], z[2]);
    z[3] = o1; z[4] = e[2]; ce(z[3], z[4]);
    z[5] = e[3];
}
DEV void merge63(const hf4 a[6], const hf4 b[3], hf4 z[9]) {
    hf4 e[5]; merge32(a[0], a[2], a[4], b[0], b[2], e);
    hf4 o[4]; merge31(a[1], a[3], a[5], b[1], o);
    z[0] = e[0];
    z[1] = o[0]; z[2] = e[1]; ce(z[1], z[2]);
    z[3] = o[1]; z[4] = e[2]; ce(z[3], z[4]);
    z[5] = o[2]; z[6] = e[3]; ce(z[5], z[6]);
    z[7] = o[3]; z[8] = e[4]; ce(z[7], z[8]);
}
DEV void merge44(const hf4 a[4], const hf4 b[4], hf4 z[8]) {
    hf4 e[4]; merge22(a[0], a[2], b[0], b[2], e);
    hf4 o[4]; merge22(a[1], a[3], b[1], b[3], o);
    z[0] = e[0];
    z[1] = o[0]; z[2] = e[1]; ce(z[1], z[2]);
    z[3] = o[1]; z[4] = e[2]; ce(z[3], z[4]);
    z[5] = o[2]; z[6] = e[3]; ce(z[5], z[6]);
    z[7] = o[3];
}
DEV void merge55(const hf4 a[5], const hf4 b[5], hf4 z[10]) {
    hf4 ae[3] = {a[0], a[2], a[4]}, be[3] = {b[0], b[2], b[4]};
    hf4 e[6]; merge33(ae, be, e);
    hf4 o[4]; merge22(a[1], a[3], b[1], b[3], o);
    z[0] = e[0];
    z[1] = o[0]; z[2] = e[1]; ce(z[1], z[2]);
    z[3] = o[1]; z[4] = e[2]; ce(z[3], z[4]);
    z[5] = o[2]; z[6] = e[3]; ce(z[5], z[6]);
    z[7] = o[3]; z[8] = e[4]; ce(z[7], z[8]);
    z[9] = e[5];
}
DEV void merge99(const hf4 a[9], const hf4 b[9], hf4 z[18]) {
    hf4 ae[5] = {a[0], a[2], a[4], a[6], a[8]};
    hf4 be[5] = {b[0], b[2], b[4], b[6], b[8]};
    hf4 e[10]; merge55(ae, be, e);
    hf4 ao[4] = {a[1], a[3], a[5], a[7]};
    hf4 bo[4] = {b[1], b[3], b[5], b[7]};
    hf4 o[8]; merge44(ao, bo, o);
    z[0] = e[0];
#pragma unroll
    for (int i = 0; i < 8; i++) {
        z[2 * i + 1] = o[i];
        z[2 * i + 2] = e[i + 1];
        ce(z[2 * i + 1], z[2 * i + 2]);
    }
    z[17] = e[9];
}

// rank-13-of-27, tree form (identity verified exact in round 1).
DEV hf4 sel13(const hf4 E[18], const hf4 R[9]) {
    hf4 t0 = hmax4(R[0], E[12]), t1 = hmax4(R[1], E[11]);
    hf4 t2 = hmax4(R[2], E[10]), t3 = hmax4(R[3], E[9]);
    hf4 t4 = hmax4(R[4], E[8]),  t5 = hmax4(R[5], E[7]);
    hf4 t6 = hmax4(R[6], E[6]),  t7 = hmax4(R[7], E[5]);
    hf4 t8 = hmax4(R[8], E[4]);
    hf4 a = hmin4(t0, t1), b = hmin4(t2, t3);
    hf4 c = hmin4(t4, t5), d = hmin4(t6, t7);
    hf4 e = hmin4(hmin4(a, b), hmin4(c, d));
    return hmin4(hmin4(e, t8), E[13]);
}

// Raw plane taps: 3 rows x (left, center4, right). 18 VGPRs.
struct RawP { float a[3]; f4 v[3]; float d[3]; };

// 9 asm-volatile loads (flat 64-bit vaddr + off form — always valid);
// cannot be sunk/collapsed by the compiler.
DEV void loadp(RawP& B, const float* pp, const int oL[3], const int oC[3],
               const int oR[3]) {
#pragma unroll
    for (int i = 0; i < 3; i++) {
        const float* aL = (const float*)((const char*)pp + oL[i]);
        const float* aC = (const float*)((const char*)pp + oC[i]);
        const float* aR = (const float*)((const char*)pp + oR[i]);
        asm volatile("global_load_dword %0, %1, off"
                     : "=v"(B.a[i]) : "v"(aL));
        asm volatile("global_load_dwordx4 %0, %1, off"
                     : "=v"(B.v[i]) : "v"(aC));
        asm volatile("global_load_dword %0, %1, off"
                     : "=v"(B.d[i]) : "v"(aR));
    }
}

// raw taps -> packed rows -> sorted-9 (4-wide packed). Same network as R5-R11.
DEV void sortp(const RawP& B, hf4 M[9]) {
    hf4 r[3][3];
#pragma unroll
    for (int i = 0; i < 3; i++) {
        f4 v = B.v[i];
        hf2 pAL = pk2(B.a[i], v.x);
        hf2 pAC = pk2(v.x, v.y);
        hf2 pSH = pk2(v.y, v.z);
        hf2 pBC = pk2(v.z, v.w);
        hf2 pBR = pk2(v.w, B.d[i]);
        r[i][0] = cat(pAL, pSH);
        r[i][1] = cat(pAC, pBC);
        r[i][2] = cat(pSH, pBR);
        sort3(r[i][0], r[i][1], r[i][2]);
    }
    hf4 s6[6]; merge33(r[0], r[1], s6);
    merge63(s6, r[2], M);
}

constexpr int Bb = 2, Dd = 160, Hh = 160, Ww = 160;
constexpr int HW = Hh * Ww;            // 25600
constexpr int WQ = Ww / 4;             // 40 x-quads per row
constexpr int CH = 8;                  // z-chunk per thread
constexpr int NCH = Dd / CH;           // 20
constexpr int TOTAL = Bb * NCH * Hh * WQ;  // 256,000 threads = 4000 waves

__global__ __launch_bounds__(256, 2) void MedianPool3d_68994354642979_kernel(
    const float* __restrict__ in, float* __restrict__ out) {
    int tid = blockIdx.x * 256 + threadIdx.x;
    int q = tid % WQ;
    int rest = tid / WQ;
    int y = rest % Hh;
    rest /= Hh;
    int chunk = rest % NCH;
    int b = rest / NCH;
    int x0 = q * 4;

    // reflect padding (jnp.pad mode="reflect", pad=1)
    int ym = (y == 0) ? 1 : y - 1;
    int yp = (y == Hh - 1) ? Hh - 2 : y + 1;
    int ro[3] = {ym * Ww, y * Ww, yp * Ww};
    int cL = (x0 == 0) ? 1 : x0 - 1;
    int cR = (x0 + 4 == Ww) ? (Ww - 2) : x0 + 4;

    // per-lane byte offsets within a plane
    int oL[3], oC[3], oR[3];
#pragma unroll
    for (int i = 0; i < 3; i++) {
        oL[i] = (ro[i] + cL) * 4;
        oC[i] = (ro[i] + x0) * 4;
        oR[i] = (ro[i] + cR) * 4;
    }

    const float* base = in + (size_t)b * Dd * HW;
    float* ob = out + (size_t)b * Dd * HW;
    int z0 = chunk * CH;

    // plane rel m (m in [0, CH+1]) = global plane z0-1+m, z-reflected
    auto planeptr = [&](int m) {
        int p = z0 - 1 + m;
        if (p < 0) p = -p;
        if (p >= Dd) p = 2 * Dd - 2 - p;
        return base + (size_t)p * HW;
    };

    // SS slot of plane rel m = m & 3. Ring buffer of raw planes (m>=3):
    // buf (m-3)%4: m=3..6 prologue, m=7,8 @iter0, m=9 @iter1.
    hf4 SS[4][9];
    RawP rg0, rg1, rg2, rg3;

    {   // ---- prologue: 7 plane loads, 3 sorts, max 36 outstanding ----
        RawP t0, t1, t2;
        loadp(t0, planeptr(0), oL, oC, oR);
        loadp(t1, planeptr(1), oL, oC, oR);
        loadp(t2, planeptr(2), oL, oC, oR);
        loadp(rg0, planeptr(3), oL, oC, oR);     // 36 out
        VMWAIT(27);  // m0 done
        sortp(t0, SS[0]);
        loadp(rg1, planeptr(4), oL, oC, oR);     // m1,m2,m3,m4 = 36
        VMWAIT(27);  // m1 done
        sortp(t1, SS[1]);
        loadp(rg2, planeptr(5), oL, oC, oR);     // m2..m5 = 36
        VMWAIT(27);  // m2 done
        sortp(t2, SS[2]);
        loadp(rg3, planeptr(6), oL, oC, oR);     // m3..m6 = 36
    }

    // ---- 4 iterations, manually unrolled (distinct vmcnt immediates) ----
    // iter j: outputs z=z0+2j, z+1; sorts m=2j+3 (->slot sD) and m=2j+4
    // (->retired slot sA, skipped at j=3); loads m=2j+7 / 2j+8 (j<=1).
#define ITER(J, KN, BUFA, BUFB, LD_A, LD_B, DO_B)                          \
    do {                                                                   \
        VMWAIT(KN); /* raw m=2J+3, 2J+4 resident */                        \
        const int sA = (2 * (J)) & 3, sB = (2 * (J) + 1) & 3;              \
        const int sC = (2 * (J) + 2) & 3, sD = (2 * (J) + 3) & 3;          \
        sortp(BUFA, SS[sD]); /* S[z+2] */                                  \
        if (LD_A) loadp(BUFA, planeptr(2 * (J) + 7), oL, oC, oR);          \
        hf4 E[18];                                                         \
        merge99(SS[sB], SS[sC], E);                                        \
        hf4 m0 = sel13(E, SS[sA]);                                         \
        const int z = z0 + 2 * (J);                                        \
        float* o0 = ob + (size_t)z * HW + ro[1] + x0;                      \
        *reinterpret_cast<f4*>(o0) = (f4){(float)m0.x, (float)m0.y,        \
                                          (float)m0.z, (float)m0.w};       \
        if (DO_B) sortp(BUFB, SS[sA]); /* S[z+3] into retired slot */      \
        if (LD_B) loadp(BUFB, planeptr(2 * (J) + 8), oL, oC, oR);          \
        hf4 m1 = sel13(E, SS[sD]);                                         \
        *reinterpret_cast<f4*>(o0 + HW) = (f4){(float)m1.x, (float)m1.y,   \
                                               (float)m1.z, (float)m1.w};  \
    } while (0)

    // wait-count derivation (in-order queue, oldest->newest), 9 loads/plane,
    // 1 store per output:
    // iter0: queue m3..m6 (36); need m3,m4 -> allow m5+m6            = 18
    // iter1: m5,m6,m7,st00,m8,st01 (38); need m5,m6 -> allow 20      = 20
    // iter2: m7,st00,m8,st01,m9,st10,st11 (31); need m7,m8 -> allow  = 12
    // iter3: m9,st10,st11,st20,st21 (13); need m9 -> allow 4         = 4
    ITER(0, 18, rg0, rg1, true,  true,  true);
    ITER(1, 20, rg2, rg3, true,  false, true);
    ITER(2, 12, rg0, rg1, false, false, true);
    ITER(3, 4,  rg2, rg3, false, false, false);
#undef ITER
}

extern "C" void kernel_launch(void* const* d_in, const int* in_sizes, int n_in,
                              void* d_out, int out_size, void* d_ws, size_t ws_size,
                              hipStream_t stream) {
    const float* x = (const float*)d_in[0];
    float* out = (float*)d_out;
    constexpr int threads = 256;
    constexpr int blocks = TOTAL / threads;  // 1000 exactly
    MedianPool3d_68994354642979_kernel<<<blocks, threads, 0, stream>>>(x, out);
}